// Round 1
// baseline (211.810 us; speedup 1.0000x reference)
//
#include <hip/hip_runtime.h>
#include <math.h>

#define NQ 10
#define NSTATE 1024
#define WW 113
#define BB 16
#define CC 22
#define KK 16
#define NF 8
#define FDIM 352   // CC*NF*2
#define NS (BB*WW) // 1808

__device__ __forceinline__ int ins0(int j, int p) {
    return ((j >> p) << (p + 1)) | (j & ((1 << p) - 1));
}

// ---------------- Kernel A: windows -> DFT feats -> projection -> angles ----
__global__ __launch_bounds__(64) void feat_proj_kernel(
    const float* __restrict__ x,       // (B, C, 128)
    const float* __restrict__ proj_w,  // (10, 352)
    const float* __restrict__ proj_b,  // (10,)
    float* __restrict__ angles)        // (NS, 10)
{
    const int s = blockIdx.x;
    const int b = s / WW, w = s % WW;
    const int t = threadIdx.x;

    __shared__ float win[CC * KK];
    __shared__ float twre[16], twim[16];

    for (int e = t; e < CC * KK; e += 64) {
        int c = e >> 4, n = e & 15;
        win[e] = x[b * (CC * 128) + c * 128 + w + n];
    }
    if (t < 16) {
        float ang = -(float)M_PI * (float)t / 8.0f;
        twre[t] = cosf(ang);
        twim[t] = sinf(ang);
    }
    __syncthreads();

    float acc[10];
#pragma unroll
    for (int q = 0; q < 10; ++q) acc[q] = 0.f;

    for (int pidx = t; pidx < CC * NF; pidx += 64) {
        int c = pidx >> 3, k = pidx & 7;
        float re = 0.f, im = 0.f;
#pragma unroll
        for (int n = 0; n < 16; ++n) {
            int m = (k * n) & 15;
            float xv = win[c * 16 + n];
            re += xv * twre[m];
            im += xv * twim[m];
        }
        float mag = log1pf(sqrtf(re * re + im * im));
        float ang = atan2f(im, re) * (float)(1.0 / M_PI);
        int j0 = c * 16 + k * 2;
#pragma unroll
        for (int q = 0; q < 10; ++q)
            acc[q] += mag * proj_w[q * FDIM + j0] + ang * proj_w[q * FDIM + j0 + 1];
    }
#pragma unroll
    for (int q = 0; q < 10; ++q) {
        float v = acc[q];
        for (int off = 32; off > 0; off >>= 1) v += __shfl_xor(v, off);
        acc[q] = v;
    }
    if (t == 0) {
#pragma unroll
        for (int q = 0; q < 10; ++q)
            angles[s * 10 + q] = tanhf(acc[q] + proj_b[q]) * (float)M_PI;
    }
}

// ---------------- Kernel B: statevector circuit --------------------------
__device__ __forceinline__ void apply_u3(float* sre, float* sim_, int tid,
        int p, float th, float ph, float lm)
{
    float ct, st, cp, sp, cl, sl;
    sincosf(th * 0.5f, &st, &ct);
    sincosf(ph, &sp, &cp);
    sincosf(lm, &sl, &cl);
    const float u00r = ct;
    const float u01r = -cl * st, u01i = -sl * st;
    const float u10r = cp * st,  u10i = sp * st;
    const float u11r = (cp * cl - sp * sl) * ct, u11i = (sp * cl + cp * sl) * ct;
#pragma unroll
    for (int it = 0; it < 2; ++it) {
        int j = tid + it * 256;
        int i0 = ins0(j, p), i1 = i0 | (1 << p);
        float ar = sre[i0], ai = sim_[i0], br = sre[i1], bi = sim_[i1];
        sre[i0]  = u00r * ar + u01r * br - u01i * bi;
        sim_[i0] = u00r * ai + u01r * bi + u01i * br;
        sre[i1]  = u10r * ar - u10i * ai + u11r * br - u11i * bi;
        sim_[i1] = u10r * ai + u10i * ar + u11r * bi + u11i * br;
    }
    __syncthreads();
}

__device__ __forceinline__ void apply_ising(float* sre, float* sim_, int tid,
        int p1, int p2, float tzz, float tyy, float txx)
{
    float czz, szz; sincosf(tzz * 0.5f, &szz, &czz);
    float cy, sy;   sincosf(tyy * 0.5f, &sy, &cy);
    float cx, sx;   sincosf(txx * 0.5f, &sx, &cx);
    const int mask = (1 << p1) | (1 << p2);
#pragma unroll
    for (int it = 0; it < 2; ++it) {
        int j = tid + it * 256;
        int i0 = ins0(j, p1);        // bit p1 == 0
        int i1 = i0 ^ mask;
        bool eq = ((i0 >> p2) & 1) == 0;   // b1==b2 iff b2==0 here
        float pzi = eq ? -szz : szz;       // zz phase = (czz, pzi), same for both
        float ur = sre[i0], ui = sim_[i0], vr = sre[i1], vi = sim_[i1];
        float tur = czz * ur - pzi * ui, tui = czz * ui + pzi * ur;
        float tvr = czz * vr - pzi * vi, tvi = czz * vi + pzi * vr;
        float syg = eq ? -sy : sy;         // yy: new = c*z - i*s*sgn*partner
        float yur = cy * tur + syg * tvi, yui = cy * tui - syg * tvr;
        float yvr = cy * tvr + syg * tui, yvi = cy * tvi - syg * tur;
        sre[i0]  = cx * yur + sx * yvi;    // xx: new = c*z - i*s*partner
        sim_[i0] = cx * yui - sx * yvr;
        sre[i1]  = cx * yvr + sx * yui;
        sim_[i1] = cx * yvi - sx * yur;
    }
    __syncthreads();
}

__device__ __forceinline__ void apply_cu3(float* sre, float* sim_, int tid,
        int pc, int pt, float th, float ph, float lm)
{
    float ct, st, cp, sp, cl, sl;
    sincosf(th * 0.5f, &st, &ct);
    sincosf(ph, &sp, &cp);
    sincosf(lm, &sl, &cl);
    const float u00r = ct;
    const float u01r = -cl * st, u01i = -sl * st;
    const float u10r = cp * st,  u10i = sp * st;
    const float u11r = (cp * cl - sp * sl) * ct, u11i = (sp * cl + cp * sl) * ct;
    const int pl = pc < pt ? pc : pt;
    const int ph2 = pc < pt ? pt : pc;
    {
        int j = tid;              // exactly 256 pairs
        int t1 = ins0(j, pl);
        int base = ins0(t1, ph2);
        int i0 = base | (1 << pc);      // control=1, target=0
        int i1 = i0 | (1 << pt);        // control=1, target=1
        float ar = sre[i0], ai = sim_[i0], br = sre[i1], bi = sim_[i1];
        sre[i0]  = u00r * ar + u01r * br - u01i * bi;
        sim_[i0] = u00r * ai + u01r * bi + u01i * br;
        sre[i1]  = u10r * ar - u10i * ai + u11r * br - u11i * bi;
        sim_[i1] = u10r * ai + u10i * ar + u11r * bi + u11i * br;
    }
    __syncthreads();
}

__global__ __launch_bounds__(256) void circuit_kernel(
    const float* __restrict__ angles,      // (NS, 10)
    const float* __restrict__ freq_scale,  // (10,)
    const float* __restrict__ conv_params, // (3,10,15)
    const float* __restrict__ pool_params, // (3,5,3)
    float* __restrict__ ev)                // (NS,)
{
    const int s = blockIdx.x;
    const int tid = threadIdx.x;
    __shared__ float sre[NSTATE], sim_[NSTATE];
    __shared__ float vre[2 * NQ], vim[2 * NQ];
    __shared__ float part[4];

    if (tid < NQ) {
        float a = angles[s * 10 + tid];
        float bf = freq_scale[tid] * a;
        float ca, sa, cb, sb;
        sincosf(a * 0.5f, &sa, &ca);
        sincosf(bf * 0.5f, &sb, &cb);
        // v = RX(b)*RY(a)*|0> = [cb*ca - i sb*sa, cb*sa - i sb*ca]
        vre[2 * tid]     = cb * ca;  vim[2 * tid]     = -sb * sa;
        vre[2 * tid + 1] = cb * sa;  vim[2 * tid + 1] = -sb * ca;
    }
    __syncthreads();

    for (int idx = tid; idx < NSTATE; idx += 256) {
        float r = 1.f, i = 0.f;
#pragma unroll
        for (int q = 0; q < NQ; ++q) {
            int bit = (idx >> (9 - q)) & 1;
            float wr = vre[2 * q + bit], wi = vim[2 * q + bit];
            float nr = r * wr - i * wi;
            float ni = r * wi + i * wr;
            r = nr; i = ni;
        }
        sre[idx] = r; sim_[idx] = i;
    }
    __syncthreads();

    int wires[NQ];
    for (int q = 0; q < NQ; ++q) wires[q] = q;
    int nw = NQ;
    for (int layer = 0; layer < 3; ++layer) {
        const float* wp = conv_params + layer * NQ * 15;
        for (int parity = 0; parity < 2; ++parity) {
            for (int i2 = 0; i2 + 1 < nw; ++i2) {
                if ((i2 & 1) != parity) continue;
                int wq = wires[i2], nxt = wires[i2 + 1];
                int p1 = 9 - wq, p2 = 9 - nxt;
                apply_u3(sre, sim_, tid, p1, wp[i2*15+0],  wp[i2*15+1],  wp[i2*15+2]);
                apply_u3(sre, sim_, tid, p2, wp[(i2+1)*15+3], wp[(i2+1)*15+4], wp[(i2+1)*15+5]);
                apply_ising(sre, sim_, tid, p1, p2, wp[i2*15+6], wp[i2*15+7], wp[i2*15+8]);
                apply_u3(sre, sim_, tid, p1, wp[i2*15+9],  wp[i2*15+10], wp[i2*15+11]);
                apply_u3(sre, sim_, tid, p2, wp[(i2+1)*15+12], wp[(i2+1)*15+13], wp[(i2+1)*15+14]);
            }
        }
        const float* pp = pool_params + layer * 5 * 3;
        for (int i2 = 1; i2 < nw; i2 += 2) {
            int pc = 9 - wires[i2], pt = 9 - wires[i2 - 1];
            apply_cu3(sre, sim_, tid, pc, pt, pp[(i2/2)*3+0], pp[(i2/2)*3+1], pp[(i2/2)*3+2]);
        }
        int nn = 0;
        for (int q = 0; q < nw; q += 2) wires[nn++] = wires[q];
        nw = nn;
    }

    float local = 0.f;
    for (int idx = tid; idx < NSTATE; idx += 256) {
        float r = sre[idx], i = sim_[idx];
        float p = r * r + i * i;
        local += (idx < 512) ? p : -p;   // qubit 0 = bit 9
    }
    for (int off = 32; off > 0; off >>= 1) local += __shfl_xor(local, off);
    int wv = tid >> 6;
    if ((tid & 63) == 0) part[wv] = local;
    __syncthreads();
    if (tid == 0) ev[s] = part[0] + part[1] + part[2] + part[3];
}

// ---------------- Kernel C: softmax-weighted aggregation ------------------
__global__ __launch_bounds__(64) void agg_kernel(
    const float* __restrict__ ev,    // (NS,)
    const float* __restrict__ aggw,  // (113,)
    float* __restrict__ out)         // (16,)
{
    const int t = threadIdx.x;
    float a0 = (t < WW) ? aggw[t] : -1e30f;
    float a1 = (t + 64 < WW) ? aggw[t + 64] : -1e30f;
    float m = fmaxf(a0, a1);
    for (int off = 32; off > 0; off >>= 1) m = fmaxf(m, __shfl_xor(m, off));
    float e0 = (t < WW) ? expf(a0 - m) : 0.f;
    float e1 = (t + 64 < WW) ? expf(a1 - m) : 0.f;
    float es = e0 + e1;
    for (int off = 32; off > 0; off >>= 1) es += __shfl_xor(es, off);
    float inv = 1.0f / es;
    for (int b = 0; b < BB; ++b) {
        float acc = 0.f;
        if (t < WW) acc += ev[b * WW + t] * e0;
        if (t + 64 < WW) acc += ev[b * WW + t + 64] * e1;
        for (int off = 32; off > 0; off >>= 1) acc += __shfl_xor(acc, off);
        if (t == 0) out[b] = acc * inv;
    }
}

extern "C" void kernel_launch(void* const* d_in, const int* in_sizes, int n_in,
                              void* d_out, int out_size, void* d_ws, size_t ws_size,
                              hipStream_t stream)
{
    const float* x           = (const float*)d_in[0];
    const float* proj_w      = (const float*)d_in[1];
    const float* proj_b      = (const float*)d_in[2];
    const float* freq_scale  = (const float*)d_in[3];
    const float* conv_params = (const float*)d_in[4];
    const float* pool_params = (const float*)d_in[5];
    const float* aggw        = (const float*)d_in[6];
    float* out = (float*)d_out;

    float* angles = (float*)d_ws;        // NS*10 floats
    float* ev     = angles + NS * 10;    // NS floats

    feat_proj_kernel<<<NS, 64, 0, stream>>>(x, proj_w, proj_b, angles);
    circuit_kernel<<<NS, 256, 0, stream>>>(angles, freq_scale, conv_params, pool_params, ev);
    agg_kernel<<<1, 64, 0, stream>>>(ev, aggw, out);
}

// Round 2
// 131.195 us; speedup vs baseline: 1.6145x; 1.6145x over previous
//
#include <hip/hip_runtime.h>
#include <math.h>

#define NQ 10
#define NSTATE 1024
#define WW 113
#define BB 16
#define CC 22
#define KK 16
#define NF 8
#define FDIM 352   // CC*NF*2
#define NS (BB*WW) // 1808
#define NGATE 23

__device__ __forceinline__ float2 cmul(float2 a, float2 b) {
    return make_float2(a.x*b.x - a.y*b.y, a.x*b.y + a.y*b.x);
}

// ---------------- gate table (static circuit structure) -------------------
// kind: 0=fused conv pair, 1=cu3 pool
__constant__ int G_KIND[NGATE]  = {0,0,0,0,0, 0,0,0,0, 1,1,1,1,1, 0,0,0,0, 1,1, 0,0, 1};
__constant__ int G_LAYER[NGATE] = {0,0,0,0,0, 0,0,0,0, 0,0,0,0,0, 1,1,1,1, 1,1, 2,2, 2};
__constant__ int G_IA[NGATE]    = {0,2,4,6,8, 1,3,5,7, 0,1,2,3,4, 0,2,1,3, 0,1, 0,1, 0};

// ---------------- matgen: build 23 fused 4x4 complex unitaries ------------
__device__ void u3mat(float2* U, float th, float ph, float lm) {
    float ct, st, cp, sp, cl, sl;
    sincosf(th * 0.5f, &st, &ct);
    sincosf(ph, &sp, &cp);
    sincosf(lm, &sl, &cl);
    U[0] = make_float2(ct, 0.f);
    U[1] = make_float2(-cl * st, -sl * st);
    U[2] = make_float2(cp * st, sp * st);
    U[3] = make_float2((cp * cl - sp * sl) * ct, (sp * cl + cp * sl) * ct);
}

__device__ void mm4(float2* C, const float2* A, const float2* B) {
#pragma unroll
    for (int i = 0; i < 4; ++i)
#pragma unroll
        for (int j = 0; j < 4; ++j) {
            float2 acc = make_float2(0.f, 0.f);
#pragma unroll
            for (int k = 0; k < 4; ++k) {
                float2 p = cmul(A[i*4+k], B[k*4+j]);
                acc.x += p.x; acc.y += p.y;
            }
            C[i*4+j] = acc;
        }
}

__global__ __launch_bounds__(64) void matgen_kernel(
    const float* __restrict__ conv,   // (3,10,15)
    const float* __restrict__ pool,   // (3,5,3)
    float2* __restrict__ mats)        // (23,16)
{
    int g = threadIdx.x;
    if (g >= NGATE) return;
    int kind = G_KIND[g], layer = G_LAYER[g], ia = G_IA[g];
    float2 F[16];
    if (kind == 0) {
        const float* wp = conv + layer * 150;
        float2 Uw0[4], Un0[4], Uw1[4], Un1[4];
        u3mat(Uw0, wp[ia*15+0], wp[ia*15+1], wp[ia*15+2]);
        u3mat(Un0, wp[(ia+1)*15+3], wp[(ia+1)*15+4], wp[(ia+1)*15+5]);
        u3mat(Uw1, wp[ia*15+9], wp[ia*15+10], wp[ia*15+11]);
        u3mat(Un1, wp[(ia+1)*15+12], wp[(ia+1)*15+13], wp[(ia+1)*15+14]);
        float2 Kpre[16], Kpost[16];
#pragma unroll
        for (int a = 0; a < 2; ++a)
#pragma unroll
        for (int b = 0; b < 2; ++b)
#pragma unroll
        for (int c = 0; c < 2; ++c)
#pragma unroll
        for (int d = 0; d < 2; ++d) {
            Kpre [(2*a+b)*4 + (2*c+d)] = cmul(Uw0[a*2+c], Un0[b*2+d]);
            Kpost[(2*a+b)*4 + (2*c+d)] = cmul(Uw1[a*2+c], Un1[b*2+d]);
        }
        // ising fused M = XX @ YY @ ZZ
        float cz, sz, cy, sy, cx, sx;
        sincosf(wp[ia*15+6] * 0.5f, &sz, &cz);
        sincosf(wp[ia*15+7] * 0.5f, &sy, &cy);
        sincosf(wp[ia*15+8] * 0.5f, &sx, &cx);
        float2 Z[16], Y[16], X[16];
#pragma unroll
        for (int k = 0; k < 16; ++k) { Z[k] = make_float2(0,0); Y[k] = make_float2(0,0); X[k] = make_float2(0,0); }
        Z[0]  = make_float2(cz, -sz); Z[5]  = make_float2(cz, sz);
        Z[10] = make_float2(cz,  sz); Z[15] = make_float2(cz, -sz);
        Y[0] = Y[5] = Y[10] = Y[15] = make_float2(cy, 0);
        Y[0*4+3] = make_float2(0,  sy); Y[1*4+2] = make_float2(0, -sy);
        Y[2*4+1] = make_float2(0, -sy); Y[3*4+0] = make_float2(0,  sy);
        X[0] = X[5] = X[10] = X[15] = make_float2(cx, 0);
        X[0*4+3] = X[1*4+2] = X[2*4+1] = X[3*4+0] = make_float2(0, -sx);
        float2 T1[16], M[16], T2[16];
        mm4(T1, Y, Z);
        mm4(M, X, T1);
        mm4(T2, M, Kpre);
        mm4(F, Kpost, T2);
    } else {
        const float* pp = pool + layer * 15 + ia * 3;
        float2 U[4];
        u3mat(U, pp[0], pp[1], pp[2]);
#pragma unroll
        for (int k = 0; k < 16; ++k) F[k] = make_float2(0,0);
        F[0*4+0] = make_float2(1,0); F[1*4+1] = make_float2(1,0);
        F[2*4+2] = U[0]; F[2*4+3] = U[1];
        F[3*4+2] = U[2]; F[3*4+3] = U[3];
    }
#pragma unroll
    for (int k = 0; k < 16; ++k) mats[g*16 + k] = F[k];
}

// ---------------- fused feature + circuit kernel --------------------------
template<int PW, int PN>
__device__ __forceinline__ void gate2q(float* sre, float* sim, const float2* m, int tid)
{
    constexpr int PL = (PW < PN) ? PW : PN;
    constexpr int PH = (PW < PN) ? PN : PW;
    int t1   = ((tid >> PL) << (PL + 1)) | (tid & ((1 << PL) - 1));
    int base = ((t1  >> PH) << (PH + 1)) | (t1  & ((1 << PH) - 1));
    const int i0 = base;
    const int i1 = base | (1 << PN);
    const int i2 = base | (1 << PW);
    const int i3 = base | (1 << PW) | (1 << PN);
    float ar[4], ai[4];
    ar[0] = sre[i0]; ai[0] = sim[i0];
    ar[1] = sre[i1]; ai[1] = sim[i1];
    ar[2] = sre[i2]; ai[2] = sim[i2];
    ar[3] = sre[i3]; ai[3] = sim[i3];
    float nr[4], ni[4];
#pragma unroll
    for (int g = 0; g < 4; ++g) {
        float accr = 0.f, acci = 0.f;
#pragma unroll
        for (int h = 0; h < 4; ++h) {
            float2 mm = m[g*4 + h];
            accr += mm.x * ar[h] - mm.y * ai[h];
            acci += mm.x * ai[h] + mm.y * ar[h];
        }
        nr[g] = accr; ni[g] = acci;
    }
    sre[i0] = nr[0]; sim[i0] = ni[0];
    sre[i1] = nr[1]; sim[i1] = ni[1];
    sre[i2] = nr[2]; sim[i2] = ni[2];
    sre[i3] = nr[3]; sim[i3] = ni[3];
}

__global__ __launch_bounds__(256) void fused_kernel(
    const float* __restrict__ x,           // (16,22,128)
    const float* __restrict__ proj_w,      // (10,352)
    const float* __restrict__ proj_b,      // (10,)
    const float* __restrict__ freq_scale,  // (10,)
    const float2* __restrict__ mats_g,     // (23,16)
    float* __restrict__ ev)                // (NS,)
{
    const int s = blockIdx.x;
    const int b = s / WW, w = s % WW;
    const int tid = threadIdx.x;

    __shared__ float sre[NSTATE], sim[NSTATE];
    __shared__ float2 smats[NGATE * 16];
    __shared__ float twre[16], twim[16];
    __shared__ float angs[NQ];
    __shared__ float2 vq[2 * NQ];
    __shared__ float part[4];

    float* win  = sre;   // staging alias (state not yet live)
    float* feat = sim;

    for (int e = tid; e < NGATE * 16; e += 256) smats[e] = mats_g[e];
    for (int e = tid; e < CC * KK; e += 256) {
        int c = e >> 4, n = e & 15;
        win[e] = x[b * (CC * 128) + c * 128 + w + n];
    }
    if (tid < 16) {
        float ang = -(float)M_PI * (float)tid / 8.0f;
        twre[tid] = cosf(ang);
        twim[tid] = sinf(ang);
    }
    __syncthreads();

    // DFT features: 176 points (c,k)
    if (tid < CC * NF) {
        int c = tid >> 3, k = tid & 7;
        float re = 0.f, im = 0.f;
#pragma unroll
        for (int n = 0; n < 16; ++n) {
            int m = (k * n) & 15;
            float xv = win[c * 16 + n];
            re += xv * twre[m];
            im += xv * twim[m];
        }
        feat[c * 16 + k * 2]     = log1pf(sqrtf(re * re + im * im));
        feat[c * 16 + k * 2 + 1] = atan2f(im, re) * (float)(1.0 / M_PI);
    }
    __syncthreads();

    // projection: 10 dots of length 352 (wave v handles q = v, v+4, v+8)
    {
        int v = tid >> 6, lane = tid & 63;
        for (int q = v; q < NQ; q += 4) {
            float acc = 0.f;
            for (int e = lane; e < FDIM; e += 64) acc += feat[e] * proj_w[q * FDIM + e];
            for (int off = 32; off > 0; off >>= 1) acc += __shfl_xor(acc, off);
            if (lane == 0) angs[q] = tanhf(acc + proj_b[q]) * (float)M_PI;
        }
    }
    __syncthreads();

    if (tid < NQ) {
        float a = angs[tid];
        float bf = freq_scale[tid] * a;
        float ca, sa, cb, sb;
        sincosf(a * 0.5f, &sa, &ca);
        sincosf(bf * 0.5f, &sb, &cb);
        vq[2 * tid]     = make_float2(cb * ca, -sb * sa);
        vq[2 * tid + 1] = make_float2(cb * sa, -sb * ca);
    }
    __syncthreads();

    // product-state init (qubit q <-> bit 9-q)
    for (int idx = tid; idx < NSTATE; idx += 256) {
        float r = 1.f, i = 0.f;
#pragma unroll
        for (int q = 0; q < NQ; ++q) {
            int bit = (idx >> (9 - q)) & 1;
            float2 vv = vq[2 * q + bit];
            float nr = r * vv.x - i * vv.y;
            float ni = r * vv.y + i * vv.x;
            r = nr; i = ni;
        }
        sre[idx] = r; sim[idx] = i;
    }
    __syncthreads();

#define GATE(G, PW, PN) gate2q<PW, PN>(sre, sim, smats + (G)*16, tid); __syncthreads();
    // layer 0 conv parity0: qubit pairs (0,1)(2,3)(4,5)(6,7)(8,9) -> bits
    GATE(0, 9, 8) GATE(1, 7, 6) GATE(2, 5, 4) GATE(3, 3, 2) GATE(4, 1, 0)
    // layer 0 conv parity1: (1,2)(3,4)(5,6)(7,8)
    GATE(5, 8, 7) GATE(6, 6, 5) GATE(7, 4, 3) GATE(8, 2, 1)
    // layer 0 pool: ctrl->tgt (1->0)(3->2)(5->4)(7->6)(9->8)
    GATE(9, 8, 9) GATE(10, 6, 7) GATE(11, 4, 5) GATE(12, 2, 3) GATE(13, 0, 1)
    // layer 1 conv: (0,2)(4,6) then (2,4)(6,8)
    GATE(14, 9, 7) GATE(15, 5, 3) GATE(16, 7, 5) GATE(17, 3, 1)
    // layer 1 pool: (2->0)(6->4)
    GATE(18, 7, 9) GATE(19, 3, 5)
    // layer 2 conv: (0,4) then (4,8)
    GATE(20, 9, 5) GATE(21, 5, 1)
    // layer 2 pool: (4->0)
    GATE(22, 5, 9)
#undef GATE

    // measurement: qubit 0 = bit 9
    float local = 0.f;
    for (int idx = tid; idx < NSTATE; idx += 256) {
        float r = sre[idx], i = sim[idx];
        float p = r * r + i * i;
        local += (idx < 512) ? p : -p;
    }
    for (int off = 32; off > 0; off >>= 1) local += __shfl_xor(local, off);
    if ((tid & 63) == 0) part[tid >> 6] = local;
    __syncthreads();
    if (tid == 0) ev[s] = part[0] + part[1] + part[2] + part[3];
}

// ---------------- aggregation ---------------------------------------------
__global__ __launch_bounds__(64) void agg_kernel(
    const float* __restrict__ ev,    // (NS,)
    const float* __restrict__ aggw,  // (113,)
    float* __restrict__ out)         // (16,)
{
    const int t = threadIdx.x;
    float a0 = (t < WW) ? aggw[t] : -1e30f;
    float a1 = (t + 64 < WW) ? aggw[t + 64] : -1e30f;
    float m = fmaxf(a0, a1);
    for (int off = 32; off > 0; off >>= 1) m = fmaxf(m, __shfl_xor(m, off));
    float e0 = (t < WW) ? expf(a0 - m) : 0.f;
    float e1 = (t + 64 < WW) ? expf(a1 - m) : 0.f;
    float es = e0 + e1;
    for (int off = 32; off > 0; off >>= 1) es += __shfl_xor(es, off);
    float inv = 1.0f / es;
    for (int b = 0; b < BB; ++b) {
        float acc = 0.f;
        if (t < WW) acc += ev[b * WW + t] * e0;
        if (t + 64 < WW) acc += ev[b * WW + t + 64] * e1;
        for (int off = 32; off > 0; off >>= 1) acc += __shfl_xor(acc, off);
        if (t == 0) out[b] = acc * inv;
    }
}

extern "C" void kernel_launch(void* const* d_in, const int* in_sizes, int n_in,
                              void* d_out, int out_size, void* d_ws, size_t ws_size,
                              hipStream_t stream)
{
    const float* x           = (const float*)d_in[0];
    const float* proj_w      = (const float*)d_in[1];
    const float* proj_b      = (const float*)d_in[2];
    const float* freq_scale  = (const float*)d_in[3];
    const float* conv_params = (const float*)d_in[4];
    const float* pool_params = (const float*)d_in[5];
    const float* aggw        = (const float*)d_in[6];
    float* out = (float*)d_out;

    float2* mats = (float2*)d_ws;                       // 23*16 float2 = 2944 B
    float* ev = (float*)d_ws + NGATE * 16 * 2;          // NS floats

    matgen_kernel<<<1, 64, 0, stream>>>(conv_params, pool_params, mats);
    fused_kernel<<<NS, 256, 0, stream>>>(x, proj_w, proj_b, freq_scale, mats, ev);
    agg_kernel<<<1, 64, 0, stream>>>(ev, aggw, out);
}

// Round 3
// 112.038 us; speedup vs baseline: 1.8905x; 1.1710x over previous
//
#include <hip/hip_runtime.h>
#include <math.h>

#define NQ 10
#define NSTATE 1024
#define WW 113
#define BB 16
#define CC 22
#define KK 16
#define NF 8
#define FDIM 352   // CC*NF*2
#define NS (BB*WW) // 1808
#define NGATE 23
#define SL(j) ((j) ^ (((j) >> 5) & 31))

__device__ __forceinline__ float2 cmul(float2 a, float2 b) {
    return make_float2(a.x*b.x - a.y*b.y, a.x*b.y + a.y*b.x);
}

// ---------------- gate table (static circuit structure) -------------------
__constant__ int G_KIND[NGATE]  = {0,0,0,0,0, 0,0,0,0, 1,1,1,1,1, 0,0,0,0, 1,1, 0,0, 1};
__constant__ int G_LAYER[NGATE] = {0,0,0,0,0, 0,0,0,0, 0,0,0,0,0, 1,1,1,1, 1,1, 2,2, 2};
__constant__ int G_IA[NGATE]    = {0,2,4,6,8, 1,3,5,7, 0,1,2,3,4, 0,2,1,3, 0,1, 0,1, 0};

__device__ void u3mat(float2* U, float th, float ph, float lm) {
    float ct, st, cp, sp, cl, sl;
    sincosf(th * 0.5f, &st, &ct);
    sincosf(ph, &sp, &cp);
    sincosf(lm, &sl, &cl);
    U[0] = make_float2(ct, 0.f);
    U[1] = make_float2(-cl * st, -sl * st);
    U[2] = make_float2(cp * st, sp * st);
    U[3] = make_float2((cp * cl - sp * sl) * ct, (sp * cl + cp * sl) * ct);
}

__device__ void mm4(float2* C, const float2* A, const float2* B) {
#pragma unroll
    for (int i = 0; i < 4; ++i)
#pragma unroll
        for (int j = 0; j < 4; ++j) {
            float2 acc = make_float2(0.f, 0.f);
#pragma unroll
            for (int k = 0; k < 4; ++k) {
                float2 p = cmul(A[i*4+k], B[k*4+j]);
                acc.x += p.x; acc.y += p.y;
            }
            C[i*4+j] = acc;
        }
}

// prep: gate matrices + softmax weights + zero out
__global__ __launch_bounds__(64) void prep_kernel(
    const float* __restrict__ conv,   // (3,10,15)
    const float* __restrict__ pool,   // (3,5,3)
    const float* __restrict__ aggw,   // (113,)
    float2* __restrict__ mats,        // (23,16)
    float* __restrict__ wts,          // (113,)
    float* __restrict__ out)          // (16,) -> zeroed
{
    const int t = threadIdx.x;

    // softmax over aggw[0..112]
    float a0 = (t < WW) ? aggw[t] : -1e30f;
    float a1 = (t + 64 < WW) ? aggw[t + 64] : -1e30f;
    float mx = fmaxf(a0, a1);
    for (int off = 32; off > 0; off >>= 1) mx = fmaxf(mx, __shfl_xor(mx, off));
    float e0 = (t < WW) ? expf(a0 - mx) : 0.f;
    float e1 = (t + 64 < WW) ? expf(a1 - mx) : 0.f;
    float es = e0 + e1;
    for (int off = 32; off > 0; off >>= 1) es += __shfl_xor(es, off);
    float inv = 1.0f / es;
    if (t < WW) wts[t] = e0 * inv;
    if (t + 64 < WW) wts[t + 64] = e1 * inv;
    if (t < BB) out[t] = 0.f;

    if (t >= NGATE) return;
    int kind = G_KIND[t], layer = G_LAYER[t], ia = G_IA[t];
    float2 F[16];
    if (kind == 0) {
        const float* wp = conv + layer * 150;
        float2 Uw0[4], Un0[4], Uw1[4], Un1[4];
        u3mat(Uw0, wp[ia*15+0], wp[ia*15+1], wp[ia*15+2]);
        u3mat(Un0, wp[(ia+1)*15+3], wp[(ia+1)*15+4], wp[(ia+1)*15+5]);
        u3mat(Uw1, wp[ia*15+9], wp[ia*15+10], wp[ia*15+11]);
        u3mat(Un1, wp[(ia+1)*15+12], wp[(ia+1)*15+13], wp[(ia+1)*15+14]);
        float2 Kpre[16], Kpost[16];
#pragma unroll
        for (int a = 0; a < 2; ++a)
#pragma unroll
        for (int b = 0; b < 2; ++b)
#pragma unroll
        for (int c = 0; c < 2; ++c)
#pragma unroll
        for (int d = 0; d < 2; ++d) {
            Kpre [(2*a+b)*4 + (2*c+d)] = cmul(Uw0[a*2+c], Un0[b*2+d]);
            Kpost[(2*a+b)*4 + (2*c+d)] = cmul(Uw1[a*2+c], Un1[b*2+d]);
        }
        float cz, sz, cy, sy, cx, sx;
        sincosf(wp[ia*15+6] * 0.5f, &sz, &cz);
        sincosf(wp[ia*15+7] * 0.5f, &sy, &cy);
        sincosf(wp[ia*15+8] * 0.5f, &sx, &cx);
        float2 Z[16], Y[16], X[16];
#pragma unroll
        for (int k = 0; k < 16; ++k) { Z[k] = make_float2(0,0); Y[k] = make_float2(0,0); X[k] = make_float2(0,0); }
        Z[0]  = make_float2(cz, -sz); Z[5]  = make_float2(cz, sz);
        Z[10] = make_float2(cz,  sz); Z[15] = make_float2(cz, -sz);
        Y[0] = Y[5] = Y[10] = Y[15] = make_float2(cy, 0);
        Y[0*4+3] = make_float2(0,  sy); Y[1*4+2] = make_float2(0, -sy);
        Y[2*4+1] = make_float2(0, -sy); Y[3*4+0] = make_float2(0,  sy);
        X[0] = X[5] = X[10] = X[15] = make_float2(cx, 0);
        X[0*4+3] = X[1*4+2] = X[2*4+1] = X[3*4+0] = make_float2(0, -sx);
        float2 T1[16], M[16], T2[16];
        mm4(T1, Y, Z);
        mm4(M, X, T1);
        mm4(T2, M, Kpre);
        mm4(F, Kpost, T2);
    } else {
        const float* pp = pool + layer * 15 + ia * 3;
        float2 U[4];
        u3mat(U, pp[0], pp[1], pp[2]);
#pragma unroll
        for (int k = 0; k < 16; ++k) F[k] = make_float2(0,0);
        F[0*4+0] = make_float2(1,0); F[1*4+1] = make_float2(1,0);
        F[2*4+2] = U[0]; F[2*4+3] = U[1];
        F[3*4+2] = U[2]; F[3*4+3] = U[3];
    }
#pragma unroll
    for (int k = 0; k < 16; ++k) mats[t*16 + k] = F[k];
}

// ---------------- fused feature + circuit + aggregate kernel --------------
template<int PW, int PN>
__device__ __forceinline__ void gate2q(float2* st, const float2* __restrict__ m, int tid)
{
    constexpr int PL = (PW < PN) ? PW : PN;
    constexpr int PH = (PW < PN) ? PN : PW;
    int t1   = ((tid >> PL) << (PL + 1)) | (tid & ((1 << PL) - 1));
    int base = ((t1  >> PH) << (PH + 1)) | (t1  & ((1 << PH) - 1));
    const int i0 = SL(base);
    const int i1 = SL(base | (1 << PN));
    const int i2 = SL(base | (1 << PW));
    const int i3 = SL(base | (1 << PW) | (1 << PN));
    float2 a[4];
    a[0] = st[i0]; a[1] = st[i1]; a[2] = st[i2]; a[3] = st[i3];
    float2 n[4];
#pragma unroll
    for (int g = 0; g < 4; ++g) {
        float accx = 0.f, accy = 0.f;
#pragma unroll
        for (int h = 0; h < 4; ++h) {
            float2 mm = m[g*4 + h];   // uniform address -> s_load (SGPR operand)
            accx = fmaf(mm.x, a[h].x, accx);
            accx = fmaf(-mm.y, a[h].y, accx);
            accy = fmaf(mm.x, a[h].y, accy);
            accy = fmaf(mm.y, a[h].x, accy);
        }
        n[g] = make_float2(accx, accy);
    }
    st[i0] = n[0]; st[i1] = n[1]; st[i2] = n[2]; st[i3] = n[3];
}

__global__ __launch_bounds__(256) void fused_kernel(
    const float* __restrict__ x,           // (16,22,128)
    const float* __restrict__ proj_w,      // (10,352)
    const float* __restrict__ proj_b,      // (10,)
    const float* __restrict__ freq_scale,  // (10,)
    const float2* __restrict__ mats,       // (23,16)
    const float* __restrict__ wts,         // (113,)
    float* __restrict__ out)               // (16,)
{
    const int s = blockIdx.x;
    const int b = s / WW, w = s % WW;
    const int tid = threadIdx.x;

    __shared__ float2 st[NSTATE];          // 8 KB (also staging for win/feat)
    __shared__ float twre[16], twim[16];
    __shared__ float angs[NQ];
    __shared__ float2 vq[2 * NQ];
    __shared__ float part[4];

    float* win  = (float*)st;          // 352 floats
    float* feat = (float*)st + 512;    // 352 floats

    for (int e = tid; e < CC * KK; e += 256) {
        int c = e >> 4, n = e & 15;
        win[e] = x[b * (CC * 128) + c * 128 + w + n];
    }
    if (tid < 16) {
        float ang = -(float)M_PI * (float)tid / 8.0f;
        twre[tid] = cosf(ang);
        twim[tid] = sinf(ang);
    }
    __syncthreads();

    // DFT features: 176 points (c,k)
    float fval = 0.f, fval2 = 0.f;
    if (tid < CC * NF) {
        int c = tid >> 3, k = tid & 7;
        float re = 0.f, im = 0.f;
#pragma unroll
        for (int n = 0; n < 16; ++n) {
            int m = (k * n) & 15;
            float xv = win[c * 16 + n];
            re += xv * twre[m];
            im += xv * twim[m];
        }
        fval  = log1pf(sqrtf(re * re + im * im));
        fval2 = atan2f(im, re) * (float)(1.0 / M_PI);
    }
    __syncthreads();   // done reading win before overwriting region with feat
    if (tid < CC * NF) {
        int c = tid >> 3, k = tid & 7;
        feat[c * 16 + k * 2]     = fval;
        feat[c * 16 + k * 2 + 1] = fval2;
    }
    __syncthreads();

    // projection: 10 dots of length 352
    {
        int v = tid >> 6, lane = tid & 63;
        for (int q = v; q < NQ; q += 4) {
            float acc = 0.f;
            for (int e = lane; e < FDIM; e += 64) acc += feat[e] * proj_w[q * FDIM + e];
            for (int off = 32; off > 0; off >>= 1) acc += __shfl_xor(acc, off);
            if (lane == 0) angs[q] = tanhf(acc + proj_b[q]) * (float)M_PI;
        }
    }
    __syncthreads();

    if (tid < NQ) {
        float a = angs[tid];
        float bf = freq_scale[tid] * a;
        float ca, sa, cb, sb;
        sincosf(a * 0.5f, &sa, &ca);
        sincosf(bf * 0.5f, &sb, &cb);
        vq[2 * tid]     = make_float2(cb * ca, -sb * sa);
        vq[2 * tid + 1] = make_float2(cb * sa, -sb * ca);
    }
    __syncthreads();

    // product-state init (qubit q <-> bit 9-q), swizzled slots
    for (int idx = tid; idx < NSTATE; idx += 256) {
        float r = 1.f, i = 0.f;
#pragma unroll
        for (int q = 0; q < NQ; ++q) {
            int bit = (idx >> (9 - q)) & 1;
            float2 vv = vq[2 * q + bit];
            float nr = r * vv.x - i * vv.y;
            float ni = r * vv.y + i * vv.x;
            r = nr; i = ni;
        }
        st[SL(idx)] = make_float2(r, i);
    }
    __syncthreads();

#define GATE(G, PW, PN) gate2q<PW, PN>(st, mats + (G)*16, tid); __syncthreads();
    // layer 0 conv parity0: qubit pairs (0,1)(2,3)(4,5)(6,7)(8,9) -> bits
    GATE(0, 9, 8) GATE(1, 7, 6) GATE(2, 5, 4) GATE(3, 3, 2) GATE(4, 1, 0)
    // layer 0 conv parity1: (1,2)(3,4)(5,6)(7,8)
    GATE(5, 8, 7) GATE(6, 6, 5) GATE(7, 4, 3) GATE(8, 2, 1)
    // layer 0 pool: (1->0)(3->2)(5->4)(7->6)(9->8)
    GATE(9, 8, 9) GATE(10, 6, 7) GATE(11, 4, 5) GATE(12, 2, 3) GATE(13, 0, 1)
    // layer 1 conv: (0,2)(4,6) then (2,4)(6,8)
    GATE(14, 9, 7) GATE(15, 5, 3) GATE(16, 7, 5) GATE(17, 3, 1)
    // layer 1 pool: (2->0)(6->4)
    GATE(18, 7, 9) GATE(19, 3, 5)
    // layer 2 conv: (0,4) then (4,8)
    GATE(20, 9, 5) GATE(21, 5, 1)
    // layer 2 pool: (4->0)
    GATE(22, 5, 9)
#undef GATE

    // measurement: slot bit 9 == logical bit 9 (swizzle only touches bits 0-4)
    float local = 0.f;
    for (int idx = tid; idx < NSTATE; idx += 256) {
        float2 am = st[idx];
        float p = am.x * am.x + am.y * am.y;
        local += (idx < 512) ? p : -p;
    }
    for (int off = 32; off > 0; off >>= 1) local += __shfl_xor(local, off);
    if ((tid & 63) == 0) part[tid >> 6] = local;
    __syncthreads();
    if (tid == 0) {
        float ev = part[0] + part[1] + part[2] + part[3];
        atomicAdd(&out[b], ev * wts[w]);
    }
}

extern "C" void kernel_launch(void* const* d_in, const int* in_sizes, int n_in,
                              void* d_out, int out_size, void* d_ws, size_t ws_size,
                              hipStream_t stream)
{
    const float* x           = (const float*)d_in[0];
    const float* proj_w      = (const float*)d_in[1];
    const float* proj_b      = (const float*)d_in[2];
    const float* freq_scale  = (const float*)d_in[3];
    const float* conv_params = (const float*)d_in[4];
    const float* pool_params = (const float*)d_in[5];
    const float* aggw        = (const float*)d_in[6];
    float* out = (float*)d_out;

    float2* mats = (float2*)d_ws;                 // 23*16 float2
    float* wts   = (float*)d_ws + NGATE * 16 * 2; // 113 floats

    prep_kernel<<<1, 64, 0, stream>>>(conv_params, pool_params, aggw, mats, wts, out);
    fused_kernel<<<NS, 256, 0, stream>>>(x, proj_w, proj_b, freq_scale, mats, wts, out);
}